// Round 12
// baseline (359.240 us; speedup 1.0000x reference)
//
#include <hip/hip_runtime.h>

// GraphRec VC_Aggregator — bf16 MFMA, round 12: 256-thr blocks for occupancy
// granularity. R11 lesson: VGPR_Count(124) excludes MFMA accumulators in the
// unified file -> true ~140 regs -> 512-thr (2 waves/SIMD) blocks can't fit
// x2. 256-thr block = 1 wave/SIMD -> 3 blocks/CU at 140 regs (LDS caps at 3
// too: 51.5KB x3). Wave owns 32 cols (2 N-tiles, acc[2][4]); weight frags
// streamed per K-step inside the loop (live wf = 2 frags).

#define NB 4
#define NTHR 256

// d_ws fragment layout (units of 8-short frags): [s][kg][col]
#define WS_W1 0
#define WS_W2 4096
#define WS_A1 6144
#define WS_A2 10240
#define WS_FRAGS 12288   // * 16B = 196608 bytes

typedef __attribute__((ext_vector_type(8))) short short8;   // 8 bf16 (4 VGPR)
typedef __attribute__((ext_vector_type(4))) float f32x4;

__device__ __forceinline__ float relu_f(float x) { return x > 0.f ? x : 0.f; }

__device__ __forceinline__ short f2bf(float f) {  // RNE float->bf16 bits
  union { float f; unsigned u; } v; v.f = f;
  unsigned r = v.u + 0x7FFFu + ((v.u >> 16) & 1u);
  return (short)(r >> 16);
}

__device__ __forceinline__ float bf2f(short s) {
  union { unsigned u; float f; } v; v.u = ((unsigned)(unsigned short)s) << 16;
  return v.f;
}

__device__ __forceinline__ short8 cvt8(float4 a, float4 b) {
  short8 r;
  r[0] = f2bf(a.x); r[1] = f2bf(a.y); r[2] = f2bf(a.z); r[3] = f2bf(a.w);
  r[4] = f2bf(b.x); r[5] = f2bf(b.y); r[6] = f2bf(b.z); r[7] = f2bf(b.w);
  return r;
}

// Weight B-fragment from fp32 (fallback path)
__device__ __forceinline__ short8 wfrag(const float* __restrict__ W, int ldk,
                                        int d, int k) {
  const float4* p = (const float4*)(W + (size_t)d * ldk + k);
  return cvt8(p[0], p[1]);
}

// ---- pre-kernel: convert 4 weight matrices to bf16 frag layout in ws ----
__global__ __launch_bounds__(256)
void conv_weights(const float* __restrict__ w1, const float* __restrict__ w2,
                  const float* __restrict__ a1w, const float* __restrict__ a2w,
                  short* __restrict__ ws) {
  const int id = blockIdx.x * 256 + threadIdx.x;  // 0..12287
  const float* W; int ldk, base;
  if (id < WS_W2)      { W = w1;  ldk = 256; base = WS_W1; }
  else if (id < WS_A1) { W = w2;  ldk = 128; base = WS_W2; }
  else if (id < WS_A2) { W = a1w; ldk = 256; base = WS_A1; }
  else                 { W = a2w; ldk = 128; base = WS_A2; }
  const int local = id - base;
  const int col = local & 127, kg = (local >> 7) & 3, s = local >> 9;
  const float4* p = (const float4*)(W + (size_t)col * ldk + s * 32 + kg * 8);
  *(short8*)(ws + (size_t)id * 8) = cvt8(p[0], p[1]);
}

// A-frags from swizzled LDS; 2 N-tiles x 4 M-tiles; wf streamed per K-step.
template <int NS, int ROWB>
__device__ __forceinline__ void run_phase2(const char* __restrict__ Abase,
                                           const short* __restrict__ wsf,
                                           int wsBase,
                                           const float* __restrict__ Wfb,
                                           int ldk, int usePre,
                                           f32x4 acc[2][4], int r16, int kg,
                                           int col0) {
#pragma unroll
  for (int nt = 0; nt < 2; ++nt)
#pragma unroll
    for (int mt = 0; mt < 4; ++mt) acc[nt][mt] = (f32x4){0.f, 0.f, 0.f, 0.f};
#pragma unroll
  for (int s = 0; s < NS; ++s) {
    short8 wfa, wfb;
    if (usePre) {
      const size_t base = (size_t)(wsBase + (s * 4 + kg) * 128 + col0) * 8;
      wfa = *(const short8*)(wsf + base);
      wfb = *(const short8*)(wsf + base + 128);  // col0+16
    } else {
      wfa = wfrag(Wfb, ldk, col0, s * 32 + kg * 8);
      wfb = wfrag(Wfb, ldk, col0 + 16, s * 32 + kg * 8);
    }
    const int kb = s * 64 + kg * 16;  // byte offset of this frag's k-start
#pragma unroll
    for (int mt = 0; mt < 4; ++mt) {
      const int row = mt * 16 + r16;
      short8 a = *(const short8*)(Abase + row * ROWB + (kb ^ ((row & 7) << 4)));
      acc[0][mt] = __builtin_amdgcn_mfma_f32_16x16x32_bf16(a, wfa, acc[0][mt], 0, 0, 0);
      acc[1][mt] = __builtin_amdgcn_mfma_f32_16x16x32_bf16(a, wfb, acc[1][mt], 0, 0, 0);
    }
  }
}

__global__ __launch_bounds__(NTHR, 2)
void vc_agg_kernel(const int* __restrict__ nodes,
                   const int* __restrict__ hvc,
                   const int* __restrict__ hr,
                   const float* __restrict__ c2e,
                   const float* __restrict__ v2e,
                   const float* __restrict__ r2e,
                   const float* __restrict__ w1, const float* __restrict__ b1,
                   const float* __restrict__ w2, const float* __restrict__ b2,
                   const float* __restrict__ a1w, const float* __restrict__ a1b,
                   const float* __restrict__ a2w, const float* __restrict__ a2b,
                   const float* __restrict__ a3w,
                   const short* __restrict__ wsf, int usePre,
                   float* __restrict__ out)
{
  __shared__ __align__(16) char sA3[64 * 512];  // E (p1 A) / [O|u] (p3 A), bf16 swz
  __shared__ __align__(16) char sX[64 * 256];   // X (p2 A) / A1 (p4 A), bf16 swz
  __shared__ float sU[128];
  __shared__ int sIvc[50], sIr[50];
  __shared__ float sPlog[4 * 64];
  __shared__ float sWts[64];
  __shared__ float sPs[2 * 128];

  const int tid = threadIdx.x;
  const int w = tid >> 6;          // wave 0..3 -> cols [32w, 32w+32)
  const int lane = tid & 63;
  const int r16 = lane & 15;
  const int kg = lane >> 4;        // 0..3
  const int col0 = w * 32 + r16;   // N-tile 0 col; N-tile 1 = col0+16

  const float b1v0 = b1[col0],  b1v1 = b1[col0 + 16];
  const float b2v0 = b2[col0],  b2v1 = b2[col0 + 16];
  const float a1b0 = a1b[col0], a1b1 = a1b[col0 + 16];
  const float a2b0 = a2b[col0], a2b1 = a2b[col0 + 16];
  const float a3v0 = a3w[col0], a3v1 = a3w[col0 + 16];

  const int el = tid >> 2, esub = tid & 3;  // 64 rows x 4 k-quarters

  for (int ib = 0; ib < NB; ++ib) {
    const int b = blockIdx.x * NB + ib;

    // ---- stage indices + u ----
    if (tid < 50) { sIvc[tid] = hvc[b * 50 + tid]; sIr[tid] = hr[b * 50 + tid]; }
    if (tid < 128) sU[tid] = v2e[(size_t)nodes[b] * 128 + tid];
    __syncthreads();

    // ---- stage E = [c2e|r2e] -> sA3 (bf16, swizzled) ----
    if (el < 50) {
      const int kk = esub * 64;  // 64 k per thread, single table per thread
      const float* src = (kk < 128) ? (c2e + (size_t)sIvc[el] * 128 + kk)
                                    : (r2e + (size_t)sIr[el] * 128 + (kk - 128));
#pragma unroll
      for (int j = 0; j < 8; ++j) {
        const float4* p = (const float4*)(src + j * 8);
        const int kb = (kk + j * 8) * 2;
        *(short8*)(sA3 + el * 512 + (kb ^ ((el & 7) << 4))) = cvt8(p[0], p[1]);
      }
    }
    __syncthreads();

    f32x4 acc[2][4];

    // ---- phase 1: X = relu(E @ w1^T + b1), K=256 ----
    run_phase2<8, 512>(sA3, wsf, WS_W1, w1, 256, usePre, acc, r16, kg, col0);
#pragma unroll
    for (int nt = 0; nt < 2; ++nt) {
      const float bb = nt ? b1v1 : b1v0;
      const int c = col0 + nt * 16;
#pragma unroll
      for (int mt = 0; mt < 4; ++mt)
#pragma unroll
        for (int r = 0; r < 4; ++r) {
          const int row = mt * 16 + kg * 4 + r;
          *(short*)(sX + row * 256 + ((c * 2) ^ ((row & 7) << 4))) =
              f2bf(relu_f(acc[nt][mt][r] + bb));
        }
    }
    __syncthreads();

    // ---- phase 2: O = relu(X @ w2^T + b2), K=128 ----
    run_phase2<4, 256>(sX, wsf, WS_W2, w2, 128, usePre, acc, r16, kg, col0);
#pragma unroll
    for (int nt = 0; nt < 2; ++nt) {
      const float bb = nt ? b2v1 : b2v0;
      const int c = col0 + nt * 16;
#pragma unroll
      for (int mt = 0; mt < 4; ++mt)
#pragma unroll
        for (int r = 0; r < 4; ++r) {
          const int row = mt * 16 + kg * 4 + r;
          *(short*)(sA3 + row * 512 + ((c * 2) ^ ((row & 7) << 4))) =
              f2bf(relu_f(acc[nt][mt][r] + bb));
        }
    }
    // ---- fill u into cols 128..255 of sA3 (phase-3 A = [O | u]) ----
    {
      const float* up = sU + esub * 32;
#pragma unroll
      for (int m = 0; m < 4; ++m) {
        const int kb = (128 + esub * 32 + m * 8) * 2;
        *(short8*)(sA3 + el * 512 + (kb ^ ((el & 7) << 4))) =
            cvt8(*(const float4*)(up + m * 8), *(const float4*)(up + m * 8 + 4));
      }
    }
    __syncthreads();

    // ---- phase 3: A1 = relu([O|u] @ a1w^T + a1b), K=256 ----
    run_phase2<8, 512>(sA3, wsf, WS_A1, a1w, 256, usePre, acc, r16, kg, col0);
#pragma unroll
    for (int nt = 0; nt < 2; ++nt) {
      const float bb = nt ? a1b1 : a1b0;
      const int c = col0 + nt * 16;
#pragma unroll
      for (int mt = 0; mt < 4; ++mt)
#pragma unroll
        for (int r = 0; r < 4; ++r) {
          const int row = mt * 16 + kg * 4 + r;
          *(short*)(sX + row * 256 + ((c * 2) ^ ((row & 7) << 4))) =
              f2bf(relu_f(acc[nt][mt][r] + a1b0 * 0.f + bb));
        }
    }
    __syncthreads();

    // ---- phase 4: logits = relu(A1 @ a2w^T + a2b) . a3w  (fused) ----
    run_phase2<4, 256>(sX, wsf, WS_A2, a2w, 128, usePre, acc, r16, kg, col0);
    {
#pragma unroll
      for (int mt = 0; mt < 4; ++mt) {
        float pv[4];
#pragma unroll
        for (int r = 0; r < 4; ++r) {
          float v0 = relu_f(acc[0][mt][r] + a2b0) * a3v0;
          float v1 = relu_f(acc[1][mt][r] + a2b1) * a3v1;
          float v = v0 + v1;
#pragma unroll
          for (int off = 1; off < 16; off <<= 1) v += __shfl_xor(v, off);
          pv[r] = v;  // row-sum over this wave's 32 cols
        }
        if (r16 == 0) {
#pragma unroll
          for (int r = 0; r < 4; ++r)
            sPlog[w * 64 + mt * 16 + kg * 4 + r] = pv[r];
        }
      }
    }
    __syncthreads();

    // ---- reduce logits over waves + softmax over L=50 (wave 0) ----
    if (tid < 64) {
      float s = 0.f;
#pragma unroll
      for (int ww = 0; ww < 4; ++ww) s += sPlog[ww * 64 + tid];
      float x = (tid < 50) ? s : -3.4e38f;
#pragma unroll
      for (int off = 32; off; off >>= 1) x = fmaxf(x, __shfl_xor(x, off));
      const float e = (tid < 50) ? __expf(s - x) : 0.f;
      float t = e;
#pragma unroll
      for (int off = 32; off; off >>= 1) t += __shfl_xor(t, off);
      if (tid < 50) sWts[tid] = e / t;
    }
    __syncthreads();

    // ---- out[b][d] = sum_l wts[l] * O[l][d]  (bf16 O from sA3) ----
    {
      const int d = tid & 127, g = tid >> 7;  // 2 row-groups of 25
      const int lb = g * 25, le = lb + 25;
      float s = 0.f;
      for (int l = lb; l < le; ++l) {
        const short ov = *(const short*)(sA3 + l * 512 + ((d * 2) ^ ((l & 7) << 4)));
        s = fmaf(sWts[l], bf2f(ov), s);
      }
      sPs[g * 128 + d] = s;
    }
    __syncthreads();
    if (tid < 128)
      out[(size_t)b * 128 + tid] = sPs[tid] + sPs[128 + tid];
    __syncthreads();
  }
}

extern "C" void kernel_launch(void* const* d_in, const int* in_sizes, int n_in,
                              void* d_out, int out_size, void* d_ws, size_t ws_size,
                              hipStream_t stream) {
  const int* nodes = (const int*)d_in[0];
  const int* hvc   = (const int*)d_in[1];
  const int* hr    = (const int*)d_in[2];
  const float* c2e = (const float*)d_in[3];
  const float* v2e = (const float*)d_in[4];
  const float* r2e = (const float*)d_in[5];
  const float* w1  = (const float*)d_in[6];
  const float* b1  = (const float*)d_in[7];
  const float* w2  = (const float*)d_in[8];
  const float* b2  = (const float*)d_in[9];
  const float* a1w = (const float*)d_in[10];
  const float* a1b = (const float*)d_in[11];
  const float* a2w = (const float*)d_in[12];
  const float* a2b = (const float*)d_in[13];
  const float* a3w = (const float*)d_in[14];
  float* out = (float*)d_out;

  const int usePre = (ws_size >= (size_t)WS_FRAGS * 16) ? 1 : 0;
  short* wsf = (short*)d_ws;
  if (usePre)
    conv_weights<<<WS_FRAGS / 256, 256, 0, stream>>>(w1, w2, a1w, a2w, wsf);

  vc_agg_kernel<<<4096 / NB, NTHR, 0, stream>>>(nodes, hvc, hr, c2e, v2e, r2e,
                                                w1, b1, w2, b2, a1w, a1b, a2w,
                                                a2b, a3w, wsf, usePre, out);
}